// Round 9
// baseline (400.049 us; speedup 1.0000x reference)
//
#include <hip/hip_runtime.h>
#include <math.h>

#define N_NODES 50000
#define N_EDGES 600000
#define N_GRAPHS 128
#define IN_CH 128
#define PROJ 128
#define OUT_CH 128
#define M_DIM 384        // OUT_CH*K
#define HC_DIM 384       // PROJ*K
#define CAT_DIM 1152     // 3*M
#define H1_DIM 768       // 2*M
#define EPS 1e-5f
#define SCAN_BLK 256
#define NPART 8                 // XCD count
#define PART_NODES 6250         // ceil(N_NODES / NPART)
#define NPB 64                  // blocks per partition
#define NROWB 391               // ceil(N_NODES / 128)

using bf16x8 = __attribute__((ext_vector_type(8))) short;
using f32x4  = __attribute__((ext_vector_type(4))) float;

// ---------------- helpers ----------------
__device__ inline unsigned short f2bf(float f) {   // RNE float->bf16 bits
  unsigned u = __float_as_uint(f);
  unsigned r = u + 0x7fffu + ((u >> 16) & 1u);
  return (unsigned short)(r >> 16);
}
__device__ inline float bf2f(unsigned h) {
  return __uint_as_float(h << 16);
}

__device__ inline void atomicMaxF(float* addr, float val) {
  int iv = __float_as_int(val);
  if (iv >= 0) atomicMax((int*)addr, iv);
  else         atomicMin((unsigned int*)addr, (unsigned int)iv);
}
__device__ inline void atomicMinF(float* addr, float val) {
  int iv = __float_as_int(val);
  if (iv >= 0) atomicMin((int*)addr, iv);
  else         atomicMax((unsigned int*)addr, (unsigned int)iv);
}

// async global->LDS, 16B per lane; LDS dest = wave-uniform base + lane*16
__device__ inline void gld16(const void* g, void* l) {
  __builtin_amdgcn_global_load_lds(
      (const __attribute__((address_space(1))) void*)g,
      (__attribute__((address_space(3))) void*)l, 16, 0, 0);
}

// ---------------- init (fused): minmax fill + batch bounds ----------------
__global__ void init_kernel(const int* __restrict__ batch, float* __restrict__ gmax,
                            float* __restrict__ gmin, int* __restrict__ start) {
  int i = blockIdx.x * blockDim.x + threadIdx.x;
  if (i < N_GRAPHS * M_DIM) {
    gmax[i] = -__builtin_inff();
    gmin[i] =  __builtin_inff();
  }
  if (i < N_NODES) {
    int b = batch[i];
    int bp = (i == 0) ? -1 : batch[i - 1];
    for (int g = bp + 1; g <= b; ++g) start[g] = i;
    if (i == N_NODES - 1)
      for (int g = b + 1; g <= N_GRAPHS; ++g) start[g] = N_NODES;
  }
}

__global__ void cnt_from_bounds_kernel(const int* __restrict__ start, float* __restrict__ cnt) {
  int g = threadIdx.x;
  if (g < N_GRAPHS) cnt[g] = (float)(start[g + 1] - start[g]);
}

// ---------------- CSR build (XCD-partitioned) ----------------
__global__ __launch_bounds__(256) void hist_part_kernel(
    const int* __restrict__ row, const int* __restrict__ col,
    int* __restrict__ degA, int* __restrict__ degB) {
  const int part = blockIdx.x & (NPART - 1);
  const int slice = blockIdx.x >> 3;               // 0..NPB-1
  const int lo = part * PART_NODES, hi = lo + PART_NODES;
  for (int e = slice * 256 + threadIdx.x; e < N_EDGES; e += NPB * 256) {
    int r = row[e], c = col[e];
    if (c >= lo && c < hi) atomicAdd(&degA[c], 1);
    if (r >= lo && r < hi) atomicAdd(&degB[r], 1);
  }
}

__global__ __launch_bounds__(256) void fill_csr_part_kernel(
    const int* __restrict__ row, const int* __restrict__ col,
    int* __restrict__ cursA, int* __restrict__ eidxA,
    int* __restrict__ cursB, int* __restrict__ eidxB) {
  const int part = blockIdx.x & (NPART - 1);
  const int slice = blockIdx.x >> 3;
  const int lo = part * PART_NODES, hi = lo + PART_NODES;
  for (int e = slice * 256 + threadIdx.x; e < N_EDGES; e += NPB * 256) {
    int r = row[e], c = col[e];
    if (c >= lo && c < hi) eidxA[atomicAdd(&cursA[c], 1)] = r;
    if (r >= lo && r < hi) eidxB[atomicAdd(&cursB[r], 1)] = c;
  }
}

// scans fused over A/B via blockIdx.y
__global__ void scan1_kernel(const int* __restrict__ degA, const int* __restrict__ degB,
                             int* __restrict__ offsA, int* __restrict__ offsB,
                             int* __restrict__ bsumA, int* __restrict__ bsumB, int n) {
  __shared__ int sh[SCAN_BLK];
  const int* deg = blockIdx.y ? degB : degA;
  int* offs = blockIdx.y ? offsB : offsA;
  int* bsum = blockIdx.y ? bsumB : bsumA;
  int i = blockIdx.x * SCAN_BLK + threadIdx.x;
  int v = (i < n) ? deg[i] : 0;
  sh[threadIdx.x] = v; __syncthreads();
  #pragma unroll
  for (int d = 1; d < SCAN_BLK; d <<= 1) {
    int t = (threadIdx.x >= d) ? sh[threadIdx.x - d] : 0;
    __syncthreads();
    sh[threadIdx.x] += t;
    __syncthreads();
  }
  if (i < n) offs[i] = sh[threadIdx.x] - v;
  if (threadIdx.x == SCAN_BLK - 1) bsum[blockIdx.x] = sh[threadIdx.x];
}

__global__ void scan2_kernel(int* __restrict__ bsumA, int* __restrict__ bsumB, int nb) {
  __shared__ int sh[SCAN_BLK];
  int* bsum = blockIdx.y ? bsumB : bsumA;
  int v = (threadIdx.x < nb) ? bsum[threadIdx.x] : 0;
  sh[threadIdx.x] = v; __syncthreads();
  #pragma unroll
  for (int d = 1; d < SCAN_BLK; d <<= 1) {
    int t = (threadIdx.x >= d) ? sh[threadIdx.x - d] : 0;
    __syncthreads();
    sh[threadIdx.x] += t;
    __syncthreads();
  }
  if (threadIdx.x < nb) bsum[threadIdx.x] = sh[threadIdx.x] - v;
}

__global__ void scan3_kernel(int* __restrict__ offsA, int* __restrict__ offsB,
                             const int* __restrict__ bsumA, const int* __restrict__ bsumB,
                             int* __restrict__ cursA, int* __restrict__ cursB, int n) {
  int* offs = blockIdx.y ? offsB : offsA;
  const int* bsum = blockIdx.y ? bsumB : bsumA;
  int* cursor = blockIdx.y ? cursB : cursA;
  int i = blockIdx.x * SCAN_BLK + threadIdx.x;
  if (i < n) {
    int o = offs[i] + bsum[blockIdx.x];
    offs[i] = o;
    cursor[i] = o;
  }
}

// ---------------- conversions ----------------
__global__ void convert_x_kernel(const float* __restrict__ x, unsigned short* __restrict__ xnb) {
  int t = blockIdx.x * blockDim.x + threadIdx.x;
  if (t >= N_NODES * 32) return;
  int node = t >> 5;
  int c4 = (t & 31) << 2;
  float4 v = *(const float4*)(x + (size_t)node * IN_CH + c4);
  ushort4 h = {f2bf(v.x), f2bf(v.y), f2bf(v.z), f2bf(v.w)};
  *(ushort4*)(xnb + (size_t)node * 256 + 128 + c4) = h;
}

__global__ void convert_wcat_kernel(const float* __restrict__ w_rel, const float* __restrict__ w_root,
                                    unsigned short* __restrict__ wcatb) {
  int t = blockIdx.x * blockDim.x + threadIdx.x;
  if (t >= 128 * 64) return;       // 128 rows x 64 quads
  int n = t >> 6;
  int c4 = (t & 63) << 2;
  const float* src = (c4 < 128) ? (w_rel + (size_t)n * 128 + c4)
                                : (w_root + (size_t)n * 128 + (c4 - 128));
  float4 v = *(const float4*)src;
  ushort4 h = {f2bf(v.x), f2bf(v.y), f2bf(v.z), f2bf(v.w)};
  *(ushort4*)(wcatb + (size_t)n * 256 + c4) = h;
}

// convert lin_w with BN0 fold: cols c<128 scaled by bn_s[c]
__global__ void convert_linw_kernel(const float* __restrict__ lin_w, const float* __restrict__ bn_s,
                                    unsigned short* __restrict__ linwb) {
  int t = blockIdx.x * blockDim.x + threadIdx.x;
  if (t >= 384 * 96) return;       // 384 rows x 96 quads
  int n = t / 96;
  int c4 = (t - n * 96) << 2;
  float4 v = *(const float4*)(lin_w + (size_t)n * HC_DIM + c4);
  if (c4 < 128) {
    v.x *= bn_s[c4 + 0]; v.y *= bn_s[c4 + 1]; v.z *= bn_s[c4 + 2]; v.w *= bn_s[c4 + 3];
  }
  ushort4 h = {f2bf(v.x), f2bf(v.y), f2bf(v.z), f2bf(v.w)};
  *(ushort4*)(linwb + (size_t)n * HC_DIM + c4) = h;
}

// lin_b2[o] = lin_b[o] + sum_{c<128} bn_t[c] * lin_w[o][c]
__global__ void linb_fold_kernel(const float* __restrict__ lin_w, const float* __restrict__ lin_b,
                                 const float* __restrict__ bn_t, float* __restrict__ lin_b2) {
  int o = blockIdx.x * blockDim.x + threadIdx.x;
  if (o >= M_DIM) return;
  float s = lin_b[o];
  for (int c = 0; c < 128; ++c) s += bn_t[c] * lin_w[(size_t)o * HC_DIM + c];
  lin_b2[o] = s;
}

// ---------------- SpMM gather: 16 lanes/node x 16B, f32 accumulate, bf16 dst ----------------
__device__ inline void addbf8(float* a, uint4 v) {
  a[0] += bf2f(v.x & 0xffffu); a[1] += bf2f(v.x >> 16);
  a[2] += bf2f(v.y & 0xffffu); a[3] += bf2f(v.y >> 16);
  a[4] += bf2f(v.z & 0xffffu); a[5] += bf2f(v.z >> 16);
  a[6] += bf2f(v.w & 0xffffu); a[7] += bf2f(v.w >> 16);
}

__device__ inline void gather_body(const unsigned short* __restrict__ src,
                                   const int* __restrict__ eidx, int j, int end,
                                   int src_ld, int c, float* a) {
  for (; j + 3 < end; j += 4) {
    int s0 = eidx[j], s1 = eidx[j + 1], s2 = eidx[j + 2], s3 = eidx[j + 3];
    uint4 v0 = *(const uint4*)(src + (size_t)s0 * src_ld + c);
    uint4 v1 = *(const uint4*)(src + (size_t)s1 * src_ld + c);
    uint4 v2 = *(const uint4*)(src + (size_t)s2 * src_ld + c);
    uint4 v3 = *(const uint4*)(src + (size_t)s3 * src_ld + c);
    addbf8(a, v0); addbf8(a, v1); addbf8(a, v2); addbf8(a, v3);
  }
  for (; j < end; ++j) {
    uint4 v0 = *(const uint4*)(src + (size_t)eidx[j] * src_ld + c);
    addbf8(a, v0);
  }
}

__device__ inline void store_bf8(unsigned short* dst, const float* a) {
  uint4 o;
  o.x = (unsigned)f2bf(a[0]) | ((unsigned)f2bf(a[1]) << 16);
  o.y = (unsigned)f2bf(a[2]) | ((unsigned)f2bf(a[3]) << 16);
  o.z = (unsigned)f2bf(a[4]) | ((unsigned)f2bf(a[5]) << 16);
  o.w = (unsigned)f2bf(a[6]) | ((unsigned)f2bf(a[7]) << 16);
  *(uint4*)dst = o;
}

__global__ __launch_bounds__(256) void gather_bf16_kernel(
    const unsigned short* __restrict__ src, const int* __restrict__ offs,
    const int* __restrict__ ends, const int* __restrict__ eidx,
    unsigned short* __restrict__ dst, int src_ld, int dst_ld) {
  int tid = blockIdx.x * blockDim.x + threadIdx.x;
  int node = tid >> 4;       // 16 lanes per node
  int c = (tid & 15) << 3;   // 8 channels each (16B)
  if (node >= N_NODES) return;
  float a[8] = {0.f, 0.f, 0.f, 0.f, 0.f, 0.f, 0.f, 0.f};
  gather_body(src, eidx, offs[node], ends[node], src_ld, c, a);
  store_bf8(dst + (size_t)node * dst_ld + c, a);
}

// H1 gather with BN0 applied algebraically: out = bn_s[c]*(A@Xraw) + deg*bn_t[c]
__global__ __launch_bounds__(256) void gather_bn_kernel(
    const unsigned short* __restrict__ src, const int* __restrict__ offs,
    const int* __restrict__ ends, const int* __restrict__ eidx,
    const float* __restrict__ bn_s, const float* __restrict__ bn_t,
    unsigned short* __restrict__ dst, int src_ld, int dst_ld) {
  int tid = blockIdx.x * blockDim.x + threadIdx.x;
  int node = tid >> 4;
  int c = (tid & 15) << 3;
  if (node >= N_NODES) return;
  int j0 = offs[node], end = ends[node];
  float a[8] = {0.f, 0.f, 0.f, 0.f, 0.f, 0.f, 0.f, 0.f};
  gather_body(src, eidx, j0, end, src_ld, c, a);
  float deg = (float)(end - j0);
  #pragma unroll
  for (int k = 0; k < 8; ++k) a[k] = bn_s[c + k] * a[k] + deg * bn_t[c + k];
  store_bf8(dst + (size_t)node * dst_ld + c, a);
}

// ---------------- MFMA tile machinery ----------------
// LDS tile: [128 rows][64 bf16] = 128B/row, 8 slots of 16B.
// Staged with global_load_lds: LINEAR dest + pre-swizzled SOURCE (XOR involution),
// read back with the same XOR.
__device__ inline void stage_async(const unsigned short* __restrict__ src, int src_ld,
                                   int row0, int k0, char* __restrict__ zone, int t) {
  #pragma unroll
  for (int p = 0; p < 4; ++p) {
    int idx = p * 256 + t;           // 0..1023 = 128 rows x 8 slots
    int r = idx >> 3;
    int slot = idx & 7;
    int sslot = slot ^ (r & 7);
    const char* g = (const char*)(src + (size_t)(row0 + r) * src_ld + k0) + (sslot << 4);
    void* l = zone + p * 4096 + (t >> 6) * 1024;   // wave-uniform base
    gld16(g, l);
  }
}

__device__ inline bf16x8 frag_ld(const char* __restrict__ zone, int row, int slot) {
  return *(const bf16x8*)(zone + row * 128 + ((slot ^ (row & 7)) << 4));
}

// ---------------- GraphConv GEMM (2-phase dbuf) + fused column stats ----------------
// Writes RAW (pre-BN, incl bias) bf16 directly into Hcb[:,0:128].
__global__ __launch_bounds__(256) void gemm_conv_mfma(
    const unsigned short* __restrict__ xnb, const unsigned short* __restrict__ wcatb,
    const float* __restrict__ b_rel, unsigned short* __restrict__ Hcb,
    float* __restrict__ colsum8, float* __restrict__ colsq8) {
  __shared__ char smem[65536];          // 2 x (A 16KB + B 16KB)
  const int bm = blockIdx.x * 128;
  const int t = threadIdx.x;
  const int l = t & 63;
  const int wid = t >> 6;
  const int wr = wid >> 1, wc = wid & 1;
  const int lrow = l & 15, lk = l >> 4;
  f32x4 acc[4][4];
  #pragma unroll
  for (int i = 0; i < 4; ++i)
    #pragma unroll
    for (int jn = 0; jn < 4; ++jn) acc[i][jn] = (f32x4){0.f, 0.f, 0.f, 0.f};
  stage_async(xnb, 256, bm, 0, smem, t);
  stage_async(wcatb, 256, 0, 0, smem + 16384, t);
  __syncthreads();
  int cur = 0;
  for (int st = 0; st < 4; ++st) {        // K = 256
    if (st < 3) {                          // issue next tile BEFORE compute (2-phase)
      char* nz = smem + (cur ^ 1) * 32768;
      stage_async(xnb, 256, bm, (st + 1) * 64, nz, t);
      stage_async(wcatb, 256, 0, (st + 1) * 64, nz + 16384, t);
    }
    const char* zA = smem + cur * 32768;
    const char* zB = zA + 16384;
    #pragma unroll
    for (int kk = 0; kk < 2; ++kk) {
      bf16x8 af[4], bfr[4];
      #pragma unroll
      for (int mf = 0; mf < 4; ++mf) af[mf] = frag_ld(zA, wr * 64 + mf * 16 + lrow, kk * 4 + lk);
      #pragma unroll
      for (int nf = 0; nf < 4; ++nf) bfr[nf] = frag_ld(zB, wc * 64 + nf * 16 + lrow, kk * 4 + lk);
      #pragma unroll
      for (int mf = 0; mf < 4; ++mf)
        #pragma unroll
        for (int nf = 0; nf < 4; ++nf)
          acc[mf][nf] = __builtin_amdgcn_mfma_f32_16x16x32_bf16(af[mf], bfr[nf], acc[mf][nf], 0, 0, 0);
    }
    __syncthreads();                       // drains next-tile loads (they had compute to hide under)
    cur ^= 1;
  }
  float brv[4];
  #pragma unroll
  for (int nf = 0; nf < 4; ++nf) brv[nf] = b_rel[wc * 64 + nf * 16 + lrow];
  #pragma unroll
  for (int mf = 0; mf < 4; ++mf) {
    #pragma unroll
    for (int q = 0; q < 4; ++q) {
      int r = bm + wr * 64 + mf * 16 + lk * 4 + q;
      if (r < N_NODES) {
        #pragma unroll
        for (int nf = 0; nf < 4; ++nf)
          Hcb[(size_t)r * HC_DIM + wc * 64 + nf * 16 + lrow] = f2bf(acc[mf][nf][q] + brv[nf]);
      }
    }
  }
  // fused column stats (pre-BN, f32 accumulators), LDS reduce then 8-way-split atomics
  __syncthreads();
  float* csum = (float*)smem;          // [128]
  float* csq  = (float*)(smem + 512);  // [128]
  if (t < 128) { csum[t] = 0.f; csq[t] = 0.f; }
  __syncthreads();
  #pragma unroll
  for (int nf = 0; nf < 4; ++nf) {
    int ccol = wc * 64 + nf * 16 + lrow;
    float s = 0.f, q = 0.f;
    #pragma unroll
    for (int mf = 0; mf < 4; ++mf)
      #pragma unroll
      for (int qq = 0; qq < 4; ++qq) {
        int r = bm + wr * 64 + mf * 16 + lk * 4 + qq;
        if (r < N_NODES) { float v = acc[mf][nf][qq] + brv[nf]; s += v; q += v * v; }
      }
    atomicAdd(&csum[ccol], s);
    atomicAdd(&csq[ccol], q);
  }
  __syncthreads();
  if (t < 128) {
    int cpy = (blockIdx.x & 7) * 128;
    atomicAdd(&colsum8[cpy + t], csum[t]);
    atomicAdd(&colsq8[cpy + t], csq[t]);
  }
}

// ---------------- BN0 scale/shift precompute ----------------
__global__ void bn_prep_kernel(const float* __restrict__ colsum8, const float* __restrict__ colsq8,
                               const float* __restrict__ g_, const float* __restrict__ b_,
                               float* __restrict__ bn_s, float* __restrict__ bn_t) {
  int c = threadIdx.x;
  float s1 = 0.f, s2 = 0.f;
  #pragma unroll
  for (int k = 0; k < 8; ++k) { s1 += colsum8[k * 128 + c]; s2 += colsq8[k * 128 + c]; }
  float m = s1 * (1.0f / N_NODES);
  float var = s2 * (1.0f / N_NODES) - m * m;
  float sc = g_[c] * rsqrtf(var + EPS);
  bn_s[c] = sc;
  bn_t[c] = b_[c] - m * sc;
}

// ---------------- masked GEMM (2-phase dbuf) + fused pooling epilogue, LPT ----------------
__global__ __launch_bounds__(256) void gemm_mask_mfma(
    const unsigned short* __restrict__ Hcb, const unsigned short* __restrict__ linwb,
    const float* __restrict__ lin_b2, const int* __restrict__ batch,
    float* __restrict__ gsum, float* __restrict__ gmax, float* __restrict__ gmin,
    float* __restrict__ colsumsq) {
  __shared__ char smem[65536];          // 2 x (A 16KB + B 16KB); epilogue: Y[64][132] f32
  __shared__ int bsh[128];
  // LPT: longest blocks (ybl=2, 6 K-stages) dispatched first
  const int bid = blockIdx.x;
  const int ybl = 2 - bid / NROWB;
  const int bm = (bid % NROWB) * 128;
  const int bn = ybl * 128;
  const int nstages = 2 * (ybl + 1);    // Klim = 128*(ybl+1)
  const int t = threadIdx.x;
  const int l = t & 63;
  const int wid = t >> 6;
  const int wr = wid >> 1, wc = wid & 1;
  const int lrow = l & 15, lk = l >> 4;
  f32x4 acc[4][4];
  #pragma unroll
  for (int i = 0; i < 4; ++i)
    #pragma unroll
    for (int jn = 0; jn < 4; ++jn) acc[i][jn] = (f32x4){0.f, 0.f, 0.f, 0.f};
  stage_async(Hcb, HC_DIM, bm, 0, smem, t);
  stage_async(linwb, HC_DIM, bn, 0, smem + 16384, t);
  __syncthreads();
  int cur = 0;
  for (int st = 0; st < nstages; ++st) {
    if (st + 1 < nstages) {               // issue next tile BEFORE compute (2-phase)
      char* nz = smem + (cur ^ 1) * 32768;
      stage_async(Hcb, HC_DIM, bm, (st + 1) * 64, nz, t);
      stage_async(linwb, HC_DIM, bn, (st + 1) * 64, nz + 16384, t);
    }
    const char* zA = smem + cur * 32768;
    const char* zB = zA + 16384;
    #pragma unroll
    for (int kk = 0; kk < 2; ++kk) {
      bf16x8 af[4], bfr[4];
      #pragma unroll
      for (int mf = 0; mf < 4; ++mf) af[mf] = frag_ld(zA, wr * 64 + mf * 16 + lrow, kk * 4 + lk);
      #pragma unroll
      for (int nf = 0; nf < 4; ++nf) bfr[nf] = frag_ld(zB, wc * 64 + nf * 16 + lrow, kk * 4 + lk);
      #pragma unroll
      for (int mf = 0; mf < 4; ++mf)
        #pragma unroll
        for (int nf = 0; nf < 4; ++nf)
          acc[mf][nf] = __builtin_amdgcn_mfma_f32_16x16x32_bf16(af[mf], bfr[nf], acc[mf][nf], 0, 0, 0);
    }
    __syncthreads();
    cur ^= 1;
  }
  // ---- epilogue: per-graph pooling over this 128x128 tile ----
  float lbv[4];
  #pragma unroll
  for (int nf = 0; nf < 4; ++nf) lbv[nf] = lin_b2[bn + wc * 64 + nf * 16 + lrow];
  if (t < 128) bsh[t] = (bm + t < N_NODES) ? batch[bm + t] : -1;
  float* Y = (float*)smem;             // [64][132]
  const int col = t & 127;
  const int gcol = bn + col;
  const int r0 = (t >> 7) * 32;        // rows [r0, r0+32) of the staged half
  float sq = 0.f;
  __syncthreads();                     // all MFMA LDS reads + bsh done
  for (int half = 0; half < 2; ++half) {
    if (wr == half) {
      #pragma unroll
      for (int mf = 0; mf < 4; ++mf)
        #pragma unroll
        for (int q = 0; q < 4; ++q) {
          int rr = mf * 16 + lk * 4 + q;
          #pragma unroll
          for (int nf = 0; nf < 4; ++nf)
            Y[rr * 132 + wc * 64 + nf * 16 + lrow] = acc[mf][nf][q] + lbv[nf];
        }
    }
    __syncthreads();
    int curg = -1;
    float s = 0.f, mx = 0.f, mn = 0.f;
    for (int rr = 0; rr < 32; ++rr) {
      int g = bsh[half * 64 + r0 + rr];
      if (g < 0) break;                 // sorted: OOB only at tail
      float y = Y[(r0 + rr) * 132 + col];
      sq += y * y;
      if (g != curg) {
        if (curg >= 0) {
          atomicAdd(&gsum[curg * M_DIM + gcol], s);
          atomicMaxF(&gmax[curg * M_DIM + gcol], mx);
          atomicMinF(&gmin[curg * M_DIM + gcol], mn);
        }
        curg = g; s = y; mx = y; mn = y;
      } else {
        s += y; mx = fmaxf(mx, y); mn = fminf(mn, y);
      }
    }
    if (curg >= 0) {
      atomicAdd(&gsum[curg * M_DIM + gcol], s);
      atomicMaxF(&gmax[curg * M_DIM + gcol], mx);
      atomicMinF(&gmin[curg * M_DIM + gcol], mn);
    }
    __syncthreads();
  }
  atomicAdd(&colsumsq[gcol], sq);
}

// ---------------- block reduction helper ----------------
__device__ inline float block_sum128(float v, float* red) {
  int t = threadIdx.x;
  red[t] = v; __syncthreads();
  #pragma unroll
  for (int s = 64; s >= 1; s >>= 1) {
    if (t < s) red[t] += red[t + s];
    __syncthreads();
  }
  float r = red[0];
  __syncthreads();
  return r;
}

__device__ inline void bn_write_col(float v, int col, const float* __restrict__ bg,
                                    const float* __restrict__ bb, float* __restrict__ h0T,
                                    float* red) {
  float s1 = block_sum128(v, red);
  float s2 = block_sum128(v * v, red);
  float m = s1 * (1.0f / N_GRAPHS);
  float var = s2 * (1.0f / N_GRAPHS) - m * m;
  float sc = bg[col] * rsqrtf(var + EPS);
  h0T[(size_t)col * N_GRAPHS + threadIdx.x] = (v - m) * sc + bb[col];
}

// ---------------- finalize pooling + graph-dim BN ----------------
__global__ __launch_bounds__(128) void finalize_kernel(
    const float* __restrict__ gsum, const float* __restrict__ gmax,
    const float* __restrict__ gmin, const float* __restrict__ colsumsq,
    const float* __restrict__ cnt, const float* __restrict__ bnh_g,
    const float* __restrict__ bnh_b, const float* __restrict__ bno_g,
    const float* __restrict__ bno_b, float* __restrict__ h0T) {
  __shared__ float red[128];
  int c = blockIdx.x;
  int g = threadIdx.x;
  float vsum = gsum[g * M_DIM + c];
  float colsum = block_sum128(vsum, red);
  float m = colsum * (1.0f / N_NODES);
  float var = colsumsq[c] * (1.0f / N_NODES) - m * m;
  float s = bnh_g[c] * rsqrtf(var + EPS);
  float t = bnh_b[c] - m * s;
  float cg = cnt[g];
  float hadd = s * vsum + cg * t;
  float havg = hadd / fmaxf(cg, 1.0f);
  float hmax = 0.f;
  if (cg > 0.f)
    hmax = (s >= 0.f ? s * gmax[g * M_DIM + c] : s * gmin[g * M_DIM + c]) + t;
  bn_write_col(havg, c,        bno_g, bno_b, h0T, red);
  bn_write_col(hadd, 384 + c,  bno_g, bno_b, h0T, red);
  bn_write_col(hmax, 768 + c,  bno_g, bno_b, h0T, red);
}

// ---------------- small dense layers ----------------
__global__ __launch_bounds__(128) void mlp_kernel(
    const float* __restrict__ inT, const float* __restrict__ W,
    const float* __restrict__ bias, float* __restrict__ outT, int Kdim, int do_relu) {
  __shared__ float wrow[CAT_DIM];
  int oc = blockIdx.x;
  int g = threadIdx.x;
  for (int k = g; k < Kdim; k += 128) wrow[k] = W[(size_t)oc * Kdim + k];
  __syncthreads();
  float acc = bias[oc];
  for (int k = 0; k < Kdim; ++k) acc += inT[(size_t)k * N_GRAPHS + g] * wrow[k];
  if (do_relu) acc = fmaxf(acc, 0.f);
  outT[(size_t)oc * N_GRAPHS + g] = acc;
}

__global__ __launch_bounds__(128) void head_kernel(
    const float* __restrict__ h2T, const float* __restrict__ w3,
    const float* __restrict__ b3, float* __restrict__ out) {
  int g = threadIdx.x;
  float z0 = b3[0], z1 = b3[1];
  for (int k = 0; k < M_DIM; ++k) {
    float v = h2T[(size_t)k * N_GRAPHS + g];
    z0 += v * w3[k];
    z1 += v * w3[M_DIM + k];
  }
  float mz = fmaxf(z0, z1);
  float lse = mz + logf(expf(z0 - mz) + expf(z1 - mz));
  out[g * 2 + 0] = z0 - lse;
  out[g * 2 + 1] = z1 - lse;
}

// ---------------- launch ----------------
extern "C" void kernel_launch(void* const* d_in, const int* in_sizes, int n_in,
                              void* d_out, int out_size, void* d_ws, size_t ws_size,
                              hipStream_t stream) {
  const float* x       = (const float*)d_in[0];
  const int*   row     = (const int*)d_in[1];
  const int*   col     = row + N_EDGES;
  const int*   batch   = (const int*)d_in[2];
  const float* w_rel   = (const float*)d_in[4];
  const float* b_rel   = (const float*)d_in[5];
  const float* w_root  = (const float*)d_in[6];
  const float* norm0_g = (const float*)d_in[7];
  const float* norm0_b = (const float*)d_in[8];
  const float* lin_w   = (const float*)d_in[9];
  const float* lin_b   = (const float*)d_in[10];
  const float* bnh_g   = (const float*)d_in[11];
  const float* bnh_b   = (const float*)d_in[12];
  const float* bno_g   = (const float*)d_in[13];
  const float* bno_b   = (const float*)d_in[14];
  const float* w1      = (const float*)d_in[15];
  const float* b1      = (const float*)d_in[16];
  const float* w2      = (const float*)d_in[17];
  const float* b2      = (const float*)d_in[18];
  const float* w3      = (const float*)d_in[19];
  const float* b3      = (const float*)d_in[20];
  float* out = (float*)d_out;

  char* ws = (char*)d_ws;
  size_t off = 0;
  auto allocb = [&](size_t nbytes) {
    char* p = ws + off;
    off += ((nbytes + 255) & ~(size_t)255);
    return p;
  };
  // ---- zero-init region ----
  int*   degA      = (int*)allocb(N_NODES * 4);
  int*   degB      = (int*)allocb(N_NODES * 4);
  float* gsum      = (float*)allocb((size_t)N_GRAPHS * M_DIM * 4);
  float* colsumsq  = (float*)allocb(M_DIM * 4);
  float* colsum8   = (float*)allocb(8 * PROJ * 4);
  float* colsq8    = (float*)allocb(8 * PROJ * 4);
  size_t zero_bytes = off;
  // ---- no init needed ----
  float* cnt    = (float*)allocb(N_GRAPHS * 4);
  int*   gstart = (int*)allocb((N_GRAPHS + 1) * 4);
  float* bn_s   = (float*)allocb(PROJ * 4);
  float* bn_t   = (float*)allocb(PROJ * 4);
  float* lin_b2 = (float*)allocb(M_DIM * 4);
  int*   offsA = (int*)allocb(N_NODES * 4);
  int*   cursA = (int*)allocb(N_NODES * 4);
  int*   offsB = (int*)allocb(N_NODES * 4);
  int*   cursB = (int*)allocb(N_NODES * 4);
  int*   bsumA = (int*)allocb(SCAN_BLK * 4);
  int*   bsumB = (int*)allocb(SCAN_BLK * 4);
  int*   eidxA = (int*)allocb(N_EDGES * 4);
  int*   eidxB = (int*)allocb(N_EDGES * 4);
  unsigned short* Hcb   = (unsigned short*)allocb((size_t)N_NODES * HC_DIM * 2);
  unsigned short* xnb   = (unsigned short*)allocb((size_t)N_NODES * 256 * 2);
  unsigned short* wcatb = (unsigned short*)allocb(128 * 256 * 2);
  unsigned short* linwb = (unsigned short*)allocb(384 * 384 * 2);
  float* gmax  = (float*)allocb((size_t)N_GRAPHS * M_DIM * 4);
  float* gmin  = (float*)allocb((size_t)N_GRAPHS * M_DIM * 4);
  float* h0T   = (float*)allocb((size_t)CAT_DIM * N_GRAPHS * 4);
  float* h1T   = (float*)allocb((size_t)H1_DIM * N_GRAPHS * 4);
  float* h2T   = (float*)allocb((size_t)M_DIM * N_GRAPHS * 4);

  const int NB = (N_NODES + SCAN_BLK - 1) / SCAN_BLK;

  hipMemsetAsync(d_ws, 0, zero_bytes, stream);
  init_kernel<<<(N_NODES + 255) / 256, 256, 0, stream>>>(batch, gmax, gmin, gstart);
  cnt_from_bounds_kernel<<<1, 128, 0, stream>>>(gstart, cnt);

  // CSR build (XCD-partitioned hist + fill; scans fused A/B via blockIdx.y)
  hist_part_kernel<<<NPART * NPB, 256, 0, stream>>>(row, col, degA, degB);
  scan1_kernel<<<dim3(NB, 2), SCAN_BLK, 0, stream>>>(degA, degB, offsA, offsB, bsumA, bsumB, N_NODES);
  scan2_kernel<<<dim3(1, 2), SCAN_BLK, 0, stream>>>(bsumA, bsumB, NB);
  scan3_kernel<<<dim3(NB, 2), SCAN_BLK, 0, stream>>>(offsA, offsB, bsumA, bsumB, cursA, cursB, N_NODES);
  fill_csr_part_kernel<<<NPART * NPB, 256, 0, stream>>>(row, col, cursA, eidxA, cursB, eidxB);

  // conversions (independent)
  convert_x_kernel<<<(N_NODES * 32 + 255) / 256, 256, 0, stream>>>(x, xnb);
  convert_wcat_kernel<<<(128 * 64 + 255) / 256, 256, 0, stream>>>(w_rel, w_root, wcatb);

  // neigh (bf16) = gather of bf16 x -> xnb[:,0:128]
  gather_bf16_kernel<<<(N_NODES * 16 + 255) / 256, 256, 0, stream>>>(
      xnb + 128, offsA, cursA, eidxA, xnb, 256, 256);
  // conv GEMM -> Hcb[:,0:128] bf16 RAW (pre-BN) + fused column stats
  gemm_conv_mfma<<<NROWB, 256, 0, stream>>>(xnb, wcatb, b_rel, Hcb, colsum8, colsq8);
  bn_prep_kernel<<<1, 128, 0, stream>>>(colsum8, colsq8, norm0_g, norm0_b, bn_s, bn_t);
  // fold BN0 into masked-GEMM weights/bias (small, after bn_prep)
  convert_linw_kernel<<<(384 * 96 + 255) / 256, 256, 0, stream>>>(lin_w, bn_s, linwb);
  linb_fold_kernel<<<3, 128, 0, stream>>>(lin_w, lin_b, bn_t, lin_b2);
  // H1 = A @ BN(X) = bn_s*(A@Xraw) + deg*bn_t -> Hcb[:,128:256]
  gather_bn_kernel<<<(N_NODES * 16 + 255) / 256, 256, 0, stream>>>(
      Hcb, offsB, cursB, eidxB, bn_s, bn_t, Hcb + 128, HC_DIM, HC_DIM);
  // H2 = A @ H1 -> Hcb[:,256:384]
  gather_bf16_kernel<<<(N_NODES * 16 + 255) / 256, 256, 0, stream>>>(
      Hcb + 128, offsB, cursB, eidxB, Hcb + 256, HC_DIM, HC_DIM);
  // masked GEMM (BN0-folded) + fused pooling (LPT 1D grid)
  gemm_mask_mfma<<<NROWB * 3, 256, 0, stream>>>(
      Hcb, linwb, lin_b2, batch, gsum, gmax, gmin, colsumsq);
  // readout
  finalize_kernel<<<M_DIM, 128, 0, stream>>>(gsum, gmax, gmin, colsumsq, cnt,
                                             bnh_g, bnh_b, bno_g, bno_b, h0T);
  mlp_kernel<<<H1_DIM, 128, 0, stream>>>(h0T, w1, b1, h1T, CAT_DIM, 1);
  mlp_kernel<<<M_DIM, 128, 0, stream>>>(h1T, w2, b2, h2T, H1_DIM, 1);
  head_kernel<<<1, 128, 0, stream>>>(h2T, w3, b3, out);
}

// Round 10
// 392.249 us; speedup vs baseline: 1.0199x; 1.0199x over previous
//
#include <hip/hip_runtime.h>
#include <math.h>

#define N_NODES 50000
#define N_EDGES 600000
#define N_GRAPHS 128
#define IN_CH 128
#define PROJ 128
#define OUT_CH 128
#define M_DIM 384        // OUT_CH*K
#define HC_DIM 384       // PROJ*K
#define CAT_DIM 1152     // 3*M
#define H1_DIM 768       // 2*M
#define EPS 1e-5f
#define SCAN_BLK 256
#define NPART 8                 // XCD count
#define PART_NODES 6250         // ceil(N_NODES / NPART)
#define NPB 64                  // blocks per partition
#define NROWB 391               // ceil(N_NODES / 128)

using bf16x8 = __attribute__((ext_vector_type(8))) short;
using f32x4  = __attribute__((ext_vector_type(4))) float;

// ---------------- helpers ----------------
__device__ inline unsigned short f2bf(float f) {   // RNE float->bf16 bits
  unsigned u = __float_as_uint(f);
  unsigned r = u + 0x7fffu + ((u >> 16) & 1u);
  return (unsigned short)(r >> 16);
}
__device__ inline float bf2f(unsigned h) {
  return __uint_as_float(h << 16);
}

__device__ inline void atomicMaxF(float* addr, float val) {
  int iv = __float_as_int(val);
  if (iv >= 0) atomicMax((int*)addr, iv);
  else         atomicMin((unsigned int*)addr, (unsigned int)iv);
}
__device__ inline void atomicMinF(float* addr, float val) {
  int iv = __float_as_int(val);
  if (iv >= 0) atomicMin((int*)addr, iv);
  else         atomicMax((unsigned int*)addr, (unsigned int)iv);
}

// async global->LDS, 16B per lane; LDS dest = wave-uniform base + lane*16
__device__ inline void gld16(const void* g, void* l) {
  __builtin_amdgcn_global_load_lds(
      (const __attribute__((address_space(1))) void*)g,
      (__attribute__((address_space(3))) void*)l, 16, 0, 0);
}

// ---------------- init (fused): minmax fill + batch bounds ----------------
__global__ void init_kernel(const int* __restrict__ batch, float* __restrict__ gmax,
                            float* __restrict__ gmin, int* __restrict__ start) {
  int i = blockIdx.x * blockDim.x + threadIdx.x;
  if (i < N_GRAPHS * M_DIM) {
    gmax[i] = -__builtin_inff();
    gmin[i] =  __builtin_inff();
  }
  if (i < N_NODES) {
    int b = batch[i];
    int bp = (i == 0) ? -1 : batch[i - 1];
    for (int g = bp + 1; g <= b; ++g) start[g] = i;
    if (i == N_NODES - 1)
      for (int g = b + 1; g <= N_GRAPHS; ++g) start[g] = N_NODES;
  }
}

__global__ void cnt_from_bounds_kernel(const int* __restrict__ start, float* __restrict__ cnt) {
  int g = threadIdx.x;
  if (g < N_GRAPHS) cnt[g] = (float)(start[g + 1] - start[g]);
}

// ---------------- CSR build (XCD-partitioned) ----------------
__global__ __launch_bounds__(256) void hist_part_kernel(
    const int* __restrict__ row, const int* __restrict__ col,
    int* __restrict__ degA, int* __restrict__ degB) {
  const int part = blockIdx.x & (NPART - 1);
  const int slice = blockIdx.x >> 3;               // 0..NPB-1
  const int lo = part * PART_NODES, hi = lo + PART_NODES;
  for (int e = slice * 256 + threadIdx.x; e < N_EDGES; e += NPB * 256) {
    int r = row[e], c = col[e];
    if (c >= lo && c < hi) atomicAdd(&degA[c], 1);
    if (r >= lo && r < hi) atomicAdd(&degB[r], 1);
  }
}

__global__ __launch_bounds__(256) void fill_csr_part_kernel(
    const int* __restrict__ row, const int* __restrict__ col,
    int* __restrict__ cursA, int* __restrict__ eidxA,
    int* __restrict__ cursB, int* __restrict__ eidxB) {
  const int part = blockIdx.x & (NPART - 1);
  const int slice = blockIdx.x >> 3;
  const int lo = part * PART_NODES, hi = lo + PART_NODES;
  for (int e = slice * 256 + threadIdx.x; e < N_EDGES; e += NPB * 256) {
    int r = row[e], c = col[e];
    if (c >= lo && c < hi) eidxA[atomicAdd(&cursA[c], 1)] = r;
    if (r >= lo && r < hi) eidxB[atomicAdd(&cursB[r], 1)] = c;
  }
}

// scans fused over A/B via blockIdx.y
__global__ void scan1_kernel(const int* __restrict__ degA, const int* __restrict__ degB,
                             int* __restrict__ offsA, int* __restrict__ offsB,
                             int* __restrict__ bsumA, int* __restrict__ bsumB, int n) {
  __shared__ int sh[SCAN_BLK];
  const int* deg = blockIdx.y ? degB : degA;
  int* offs = blockIdx.y ? offsB : offsA;
  int* bsum = blockIdx.y ? bsumB : bsumA;
  int i = blockIdx.x * SCAN_BLK + threadIdx.x;
  int v = (i < n) ? deg[i] : 0;
  sh[threadIdx.x] = v; __syncthreads();
  #pragma unroll
  for (int d = 1; d < SCAN_BLK; d <<= 1) {
    int t = (threadIdx.x >= d) ? sh[threadIdx.x - d] : 0;
    __syncthreads();
    sh[threadIdx.x] += t;
    __syncthreads();
  }
  if (i < n) offs[i] = sh[threadIdx.x] - v;
  if (threadIdx.x == SCAN_BLK - 1) bsum[blockIdx.x] = sh[threadIdx.x];
}

__global__ void scan2_kernel(int* __restrict__ bsumA, int* __restrict__ bsumB, int nb) {
  __shared__ int sh[SCAN_BLK];
  int* bsum = blockIdx.y ? bsumB : bsumA;
  int v = (threadIdx.x < nb) ? bsum[threadIdx.x] : 0;
  sh[threadIdx.x] = v; __syncthreads();
  #pragma unroll
  for (int d = 1; d < SCAN_BLK; d <<= 1) {
    int t = (threadIdx.x >= d) ? sh[threadIdx.x - d] : 0;
    __syncthreads();
    sh[threadIdx.x] += t;
    __syncthreads();
  }
  if (threadIdx.x < nb) bsum[threadIdx.x] = sh[threadIdx.x] - v;
}

__global__ void scan3_kernel(int* __restrict__ offsA, int* __restrict__ offsB,
                             const int* __restrict__ bsumA, const int* __restrict__ bsumB,
                             int* __restrict__ cursA, int* __restrict__ cursB, int n) {
  int* offs = blockIdx.y ? offsB : offsA;
  const int* bsum = blockIdx.y ? bsumB : bsumA;
  int* cursor = blockIdx.y ? cursB : cursA;
  int i = blockIdx.x * SCAN_BLK + threadIdx.x;
  if (i < n) {
    int o = offs[i] + bsum[blockIdx.x];
    offs[i] = o;
    cursor[i] = o;
  }
}

// ---------------- conversions ----------------
__global__ void convert_x_kernel(const float* __restrict__ x, unsigned short* __restrict__ xnb) {
  int t = blockIdx.x * blockDim.x + threadIdx.x;
  if (t >= N_NODES * 32) return;
  int node = t >> 5;
  int c4 = (t & 31) << 2;
  float4 v = *(const float4*)(x + (size_t)node * IN_CH + c4);
  ushort4 h = {f2bf(v.x), f2bf(v.y), f2bf(v.z), f2bf(v.w)};
  *(ushort4*)(xnb + (size_t)node * 256 + 128 + c4) = h;
}

__global__ void convert_wcat_kernel(const float* __restrict__ w_rel, const float* __restrict__ w_root,
                                    unsigned short* __restrict__ wcatb) {
  int t = blockIdx.x * blockDim.x + threadIdx.x;
  if (t >= 128 * 64) return;       // 128 rows x 64 quads
  int n = t >> 6;
  int c4 = (t & 63) << 2;
  const float* src = (c4 < 128) ? (w_rel + (size_t)n * 128 + c4)
                                : (w_root + (size_t)n * 128 + (c4 - 128));
  float4 v = *(const float4*)src;
  ushort4 h = {f2bf(v.x), f2bf(v.y), f2bf(v.z), f2bf(v.w)};
  *(ushort4*)(wcatb + (size_t)n * 256 + c4) = h;
}

// convert lin_w with BN0 fold: cols c<128 scaled by bn_s[c]
__global__ void convert_linw_kernel(const float* __restrict__ lin_w, const float* __restrict__ bn_s,
                                    unsigned short* __restrict__ linwb) {
  int t = blockIdx.x * blockDim.x + threadIdx.x;
  if (t >= 384 * 96) return;       // 384 rows x 96 quads
  int n = t / 96;
  int c4 = (t - n * 96) << 2;
  float4 v = *(const float4*)(lin_w + (size_t)n * HC_DIM + c4);
  if (c4 < 128) {
    v.x *= bn_s[c4 + 0]; v.y *= bn_s[c4 + 1]; v.z *= bn_s[c4 + 2]; v.w *= bn_s[c4 + 3];
  }
  ushort4 h = {f2bf(v.x), f2bf(v.y), f2bf(v.z), f2bf(v.w)};
  *(ushort4*)(linwb + (size_t)n * HC_DIM + c4) = h;
}

// lin_b2[o] = lin_b[o] + sum_{c<128} bn_t[c] * lin_w[o][c]
__global__ void linb_fold_kernel(const float* __restrict__ lin_w, const float* __restrict__ lin_b,
                                 const float* __restrict__ bn_t, float* __restrict__ lin_b2) {
  int o = blockIdx.x * blockDim.x + threadIdx.x;
  if (o >= M_DIM) return;
  float s = lin_b[o];
  for (int c = 0; c < 128; ++c) s += bn_t[c] * lin_w[(size_t)o * HC_DIM + c];
  lin_b2[o] = s;
}

// ---------------- SpMM gather: 16 lanes/node x 16B, f32 accumulate, bf16 dst ----------------
__device__ inline void addbf8(float* a, uint4 v) {
  a[0] += bf2f(v.x & 0xffffu); a[1] += bf2f(v.x >> 16);
  a[2] += bf2f(v.y & 0xffffu); a[3] += bf2f(v.y >> 16);
  a[4] += bf2f(v.z & 0xffffu); a[5] += bf2f(v.z >> 16);
  a[6] += bf2f(v.w & 0xffffu); a[7] += bf2f(v.w >> 16);
}

__device__ inline void gather_body(const unsigned short* __restrict__ src,
                                   const int* __restrict__ eidx, int j, int end,
                                   int src_ld, int c, float* a) {
  for (; j + 3 < end; j += 4) {
    int s0 = eidx[j], s1 = eidx[j + 1], s2 = eidx[j + 2], s3 = eidx[j + 3];
    uint4 v0 = *(const uint4*)(src + (size_t)s0 * src_ld + c);
    uint4 v1 = *(const uint4*)(src + (size_t)s1 * src_ld + c);
    uint4 v2 = *(const uint4*)(src + (size_t)s2 * src_ld + c);
    uint4 v3 = *(const uint4*)(src + (size_t)s3 * src_ld + c);
    addbf8(a, v0); addbf8(a, v1); addbf8(a, v2); addbf8(a, v3);
  }
  for (; j < end; ++j) {
    uint4 v0 = *(const uint4*)(src + (size_t)eidx[j] * src_ld + c);
    addbf8(a, v0);
  }
}

__device__ inline void store_bf8(unsigned short* dst, const float* a) {
  uint4 o;
  o.x = (unsigned)f2bf(a[0]) | ((unsigned)f2bf(a[1]) << 16);
  o.y = (unsigned)f2bf(a[2]) | ((unsigned)f2bf(a[3]) << 16);
  o.z = (unsigned)f2bf(a[4]) | ((unsigned)f2bf(a[5]) << 16);
  o.w = (unsigned)f2bf(a[6]) | ((unsigned)f2bf(a[7]) << 16);
  *(uint4*)dst = o;
}

__global__ __launch_bounds__(256) void gather_bf16_kernel(
    const unsigned short* __restrict__ src, const int* __restrict__ offs,
    const int* __restrict__ ends, const int* __restrict__ eidx,
    unsigned short* __restrict__ dst, int src_ld, int dst_ld) {
  int tid = blockIdx.x * blockDim.x + threadIdx.x;
  int node = tid >> 4;       // 16 lanes per node
  int c = (tid & 15) << 3;   // 8 channels each (16B)
  if (node >= N_NODES) return;
  float a[8] = {0.f, 0.f, 0.f, 0.f, 0.f, 0.f, 0.f, 0.f};
  gather_body(src, eidx, offs[node], ends[node], src_ld, c, a);
  store_bf8(dst + (size_t)node * dst_ld + c, a);
}

// H1 gather with BN0 applied algebraically: out = bn_s[c]*(A@Xraw) + deg*bn_t[c]
__global__ __launch_bounds__(256) void gather_bn_kernel(
    const unsigned short* __restrict__ src, const int* __restrict__ offs,
    const int* __restrict__ ends, const int* __restrict__ eidx,
    const float* __restrict__ bn_s, const float* __restrict__ bn_t,
    unsigned short* __restrict__ dst, int src_ld, int dst_ld) {
  int tid = blockIdx.x * blockDim.x + threadIdx.x;
  int node = tid >> 4;
  int c = (tid & 15) << 3;
  if (node >= N_NODES) return;
  int j0 = offs[node], end = ends[node];
  float a[8] = {0.f, 0.f, 0.f, 0.f, 0.f, 0.f, 0.f, 0.f};
  gather_body(src, eidx, j0, end, src_ld, c, a);
  float deg = (float)(end - j0);
  #pragma unroll
  for (int k = 0; k < 8; ++k) a[k] = bn_s[c + k] * a[k] + deg * bn_t[c + k];
  store_bf8(dst + (size_t)node * dst_ld + c, a);
}

// ---------------- MFMA tile machinery (single-buffer, round-8 proven) ----------------
// LDS tile: [128 rows][64 bf16] = 128B/row, 8 slots of 16B.
// Staged with global_load_lds: LINEAR dest + pre-swizzled SOURCE (XOR involution),
// read back with the same XOR.
__device__ inline void stage_async(const unsigned short* __restrict__ src, int src_ld,
                                   int row0, int k0, char* __restrict__ zone, int t) {
  #pragma unroll
  for (int p = 0; p < 4; ++p) {
    int idx = p * 256 + t;           // 0..1023 = 128 rows x 8 slots
    int r = idx >> 3;
    int slot = idx & 7;
    int sslot = slot ^ (r & 7);
    const char* g = (const char*)(src + (size_t)(row0 + r) * src_ld + k0) + (sslot << 4);
    void* l = zone + p * 4096 + (t >> 6) * 1024;   // wave-uniform base
    gld16(g, l);
  }
}

__device__ inline bf16x8 frag_ld(const char* __restrict__ zone, int row, int slot) {
  return *(const bf16x8*)(zone + row * 128 + ((slot ^ (row & 7)) << 4));
}

// ---------------- GraphConv GEMM (single-buffer) + fused column stats ----------------
// Writes RAW (pre-BN, incl bias) bf16 directly into Hcb[:,0:128].
__global__ __launch_bounds__(256) void gemm_conv_mfma(
    const unsigned short* __restrict__ xnb, const unsigned short* __restrict__ wcatb,
    const float* __restrict__ b_rel, unsigned short* __restrict__ Hcb,
    float* __restrict__ colsum8, float* __restrict__ colsq8) {
  __shared__ char smem[32768];
  char* zoneA = smem;
  char* zoneB = smem + 16384;
  const int bm = blockIdx.x * 128;
  const int t = threadIdx.x;
  const int l = t & 63;
  const int wid = t >> 6;
  const int wr = wid >> 1, wc = wid & 1;
  const int lrow = l & 15, lk = l >> 4;
  f32x4 acc[4][4];
  #pragma unroll
  for (int i = 0; i < 4; ++i)
    #pragma unroll
    for (int jn = 0; jn < 4; ++jn) acc[i][jn] = (f32x4){0.f, 0.f, 0.f, 0.f};
  for (int st = 0; st < 4; ++st) {        // K = 256
    __syncthreads();
    stage_async(xnb, 256, bm, st * 64, zoneA, t);
    stage_async(wcatb, 256, 0, st * 64, zoneB, t);
    __syncthreads();                       // drains global_load_lds (vmcnt 0)
    #pragma unroll
    for (int kk = 0; kk < 2; ++kk) {
      bf16x8 af[4], bfr[4];
      #pragma unroll
      for (int mf = 0; mf < 4; ++mf) af[mf] = frag_ld(zoneA, wr * 64 + mf * 16 + lrow, kk * 4 + lk);
      #pragma unroll
      for (int nf = 0; nf < 4; ++nf) bfr[nf] = frag_ld(zoneB, wc * 64 + nf * 16 + lrow, kk * 4 + lk);
      #pragma unroll
      for (int mf = 0; mf < 4; ++mf)
        #pragma unroll
        for (int nf = 0; nf < 4; ++nf)
          acc[mf][nf] = __builtin_amdgcn_mfma_f32_16x16x32_bf16(af[mf], bfr[nf], acc[mf][nf], 0, 0, 0);
    }
  }
  float brv[4];
  #pragma unroll
  for (int nf = 0; nf < 4; ++nf) brv[nf] = b_rel[wc * 64 + nf * 16 + lrow];
  #pragma unroll
  for (int mf = 0; mf < 4; ++mf) {
    #pragma unroll
    for (int q = 0; q < 4; ++q) {
      int r = bm + wr * 64 + mf * 16 + lk * 4 + q;
      if (r < N_NODES) {
        #pragma unroll
        for (int nf = 0; nf < 4; ++nf)
          Hcb[(size_t)r * HC_DIM + wc * 64 + nf * 16 + lrow] = f2bf(acc[mf][nf][q] + brv[nf]);
      }
    }
  }
  // fused column stats (pre-BN, f32 accumulators), LDS reduce then 8-way-split atomics
  __syncthreads();
  float* csum = (float*)smem;          // [128]
  float* csq  = (float*)(smem + 512);  // [128]
  if (t < 128) { csum[t] = 0.f; csq[t] = 0.f; }
  __syncthreads();
  #pragma unroll
  for (int nf = 0; nf < 4; ++nf) {
    int ccol = wc * 64 + nf * 16 + lrow;
    float s = 0.f, q = 0.f;
    #pragma unroll
    for (int mf = 0; mf < 4; ++mf)
      #pragma unroll
      for (int qq = 0; qq < 4; ++qq) {
        int r = bm + wr * 64 + mf * 16 + lk * 4 + qq;
        if (r < N_NODES) { float v = acc[mf][nf][qq] + brv[nf]; s += v; q += v * v; }
      }
    atomicAdd(&csum[ccol], s);
    atomicAdd(&csq[ccol], q);
  }
  __syncthreads();
  if (t < 128) {
    int cpy = (blockIdx.x & 7) * 128;
    atomicAdd(&colsum8[cpy + t], csum[t]);
    atomicAdd(&colsq8[cpy + t], csq[t]);
  }
}

// ---------------- BN0 scale/shift precompute ----------------
__global__ void bn_prep_kernel(const float* __restrict__ colsum8, const float* __restrict__ colsq8,
                               const float* __restrict__ g_, const float* __restrict__ b_,
                               float* __restrict__ bn_s, float* __restrict__ bn_t) {
  int c = threadIdx.x;
  float s1 = 0.f, s2 = 0.f;
  #pragma unroll
  for (int k = 0; k < 8; ++k) { s1 += colsum8[k * 128 + c]; s2 += colsq8[k * 128 + c]; }
  float m = s1 * (1.0f / N_NODES);
  float var = s2 * (1.0f / N_NODES) - m * m;
  float sc = g_[c] * rsqrtf(var + EPS);
  bn_s[c] = sc;
  bn_t[c] = b_[c] - m * sc;
}

// ---------------- masked GEMM (single-buffer) + fused pooling epilogue, LPT ----------------
__global__ __launch_bounds__(256) void gemm_mask_mfma(
    const unsigned short* __restrict__ Hcb, const unsigned short* __restrict__ linwb,
    const float* __restrict__ lin_b2, const int* __restrict__ batch,
    float* __restrict__ gsum, float* __restrict__ gmax, float* __restrict__ gmin,
    float* __restrict__ colsumsq) {
  __shared__ char smem[33792];          // A 16KB + B 16KB; epilogue: Y[64][132] f32
  __shared__ int bsh[128];
  char* zoneA = smem;
  char* zoneB = smem + 16384;
  // LPT: longest blocks (ybl=2, 6 K-stages) dispatched first to kill the tail
  const int bid = blockIdx.x;
  const int ybl = 2 - bid / NROWB;
  const int bm = (bid % NROWB) * 128;
  const int bn = ybl * 128;
  const int nstages = 2 * (ybl + 1);    // Klim = 128*(ybl+1)
  const int t = threadIdx.x;
  const int l = t & 63;
  const int wid = t >> 6;
  const int wr = wid >> 1, wc = wid & 1;
  const int lrow = l & 15, lk = l >> 4;
  f32x4 acc[4][4];
  #pragma unroll
  for (int i = 0; i < 4; ++i)
    #pragma unroll
    for (int jn = 0; jn < 4; ++jn) acc[i][jn] = (f32x4){0.f, 0.f, 0.f, 0.f};
  for (int st = 0; st < nstages; ++st) {
    __syncthreads();
    stage_async(Hcb, HC_DIM, bm, st * 64, zoneA, t);
    stage_async(linwb, HC_DIM, bn, st * 64, zoneB, t);
    __syncthreads();                     // drains global_load_lds
    #pragma unroll
    for (int kk = 0; kk < 2; ++kk) {
      bf16x8 af[4], bfr[4];
      #pragma unroll
      for (int mf = 0; mf < 4; ++mf) af[mf] = frag_ld(zoneA, wr * 64 + mf * 16 + lrow, kk * 4 + lk);
      #pragma unroll
      for (int nf = 0; nf < 4; ++nf) bfr[nf] = frag_ld(zoneB, wc * 64 + nf * 16 + lrow, kk * 4 + lk);
      #pragma unroll
      for (int mf = 0; mf < 4; ++mf)
        #pragma unroll
        for (int nf = 0; nf < 4; ++nf)
          acc[mf][nf] = __builtin_amdgcn_mfma_f32_16x16x32_bf16(af[mf], bfr[nf], acc[mf][nf], 0, 0, 0);
    }
  }
  // ---- epilogue: per-graph pooling over this 128x128 tile ----
  float lbv[4];
  #pragma unroll
  for (int nf = 0; nf < 4; ++nf) lbv[nf] = lin_b2[bn + wc * 64 + nf * 16 + lrow];
  if (t < 128) bsh[t] = (bm + t < N_NODES) ? batch[bm + t] : -1;
  float* Y = (float*)smem;             // [64][132]
  const int col = t & 127;
  const int gcol = bn + col;
  const int r0 = (t >> 7) * 32;        // rows [r0, r0+32) of the staged half
  float sq = 0.f;
  __syncthreads();                     // all MFMA LDS reads + bsh done
  for (int half = 0; half < 2; ++half) {
    if (wr == half) {
      #pragma unroll
      for (int mf = 0; mf < 4; ++mf)
        #pragma unroll
        for (int q = 0; q < 4; ++q) {
          int rr = mf * 16 + lk * 4 + q;
          #pragma unroll
          for (int nf = 0; nf < 4; ++nf)
            Y[rr * 132 + wc * 64 + nf * 16 + lrow] = acc[mf][nf][q] + lbv[nf];
        }
    }
    __syncthreads();
    int curg = -1;
    float s = 0.f, mx = 0.f, mn = 0.f;
    for (int rr = 0; rr < 32; ++rr) {
      int g = bsh[half * 64 + r0 + rr];
      if (g < 0) break;                 // sorted: OOB only at tail
      float y = Y[(r0 + rr) * 132 + col];
      sq += y * y;
      if (g != curg) {
        if (curg >= 0) {
          atomicAdd(&gsum[curg * M_DIM + gcol], s);
          atomicMaxF(&gmax[curg * M_DIM + gcol], mx);
          atomicMinF(&gmin[curg * M_DIM + gcol], mn);
        }
        curg = g; s = y; mx = y; mn = y;
      } else {
        s += y; mx = fmaxf(mx, y); mn = fminf(mn, y);
      }
    }
    if (curg >= 0) {
      atomicAdd(&gsum[curg * M_DIM + gcol], s);
      atomicMaxF(&gmax[curg * M_DIM + gcol], mx);
      atomicMinF(&gmin[curg * M_DIM + gcol], mn);
    }
    __syncthreads();
  }
  atomicAdd(&colsumsq[gcol], sq);
}

// ---------------- block reduction helper ----------------
__device__ inline float block_sum128(float v, float* red) {
  int t = threadIdx.x;
  red[t] = v; __syncthreads();
  #pragma unroll
  for (int s = 64; s >= 1; s >>= 1) {
    if (t < s) red[t] += red[t + s];
    __syncthreads();
  }
  float r = red[0];
  __syncthreads();
  return r;
}

__device__ inline void bn_write_col(float v, int col, const float* __restrict__ bg,
                                    const float* __restrict__ bb, float* __restrict__ h0T,
                                    float* red) {
  float s1 = block_sum128(v, red);
  float s2 = block_sum128(v * v, red);
  float m = s1 * (1.0f / N_GRAPHS);
  float var = s2 * (1.0f / N_GRAPHS) - m * m;
  float sc = bg[col] * rsqrtf(var + EPS);
  h0T[(size_t)col * N_GRAPHS + threadIdx.x] = (v - m) * sc + bb[col];
}

// ---------------- finalize pooling + graph-dim BN ----------------
__global__ __launch_bounds__(128) void finalize_kernel(
    const float* __restrict__ gsum, const float* __restrict__ gmax,
    const float* __restrict__ gmin, const float* __restrict__ colsumsq,
    const float* __restrict__ cnt, const float* __restrict__ bnh_g,
    const float* __restrict__ bnh_b, const float* __restrict__ bno_g,
    const float* __restrict__ bno_b, float* __restrict__ h0T) {
  __shared__ float red[128];
  int c = blockIdx.x;
  int g = threadIdx.x;
  float vsum = gsum[g * M_DIM + c];
  float colsum = block_sum128(vsum, red);
  float m = colsum * (1.0f / N_NODES);
  float var = colsumsq[c] * (1.0f / N_NODES) - m * m;
  float s = bnh_g[c] * rsqrtf(var + EPS);
  float t = bnh_b[c] - m * s;
  float cg = cnt[g];
  float hadd = s * vsum + cg * t;
  float havg = hadd / fmaxf(cg, 1.0f);
  float hmax = 0.f;
  if (cg > 0.f)
    hmax = (s >= 0.f ? s * gmax[g * M_DIM + c] : s * gmin[g * M_DIM + c]) + t;
  bn_write_col(havg, c,        bno_g, bno_b, h0T, red);
  bn_write_col(hadd, 384 + c,  bno_g, bno_b, h0T, red);
  bn_write_col(hmax, 768 + c,  bno_g, bno_b, h0T, red);
}

// ---------------- small dense layers ----------------
__global__ __launch_bounds__(128) void mlp_kernel(
    const float* __restrict__ inT, const float* __restrict__ W,
    const float* __restrict__ bias, float* __restrict__ outT, int Kdim, int do_relu) {
  __shared__ float wrow[CAT_DIM];
  int oc = blockIdx.x;
  int g = threadIdx.x;
  for (int k = g; k < Kdim; k += 128) wrow[k] = W[(size_t)oc * Kdim + k];
  __syncthreads();
  float acc = bias[oc];
  for (int k = 0; k < Kdim; ++k) acc += inT[(size_t)k * N_GRAPHS + g] * wrow[k];
  if (do_relu) acc = fmaxf(acc, 0.f);
  outT[(size_t)oc * N_GRAPHS + g] = acc;
}

__global__ __launch_bounds__(128) void head_kernel(
    const float* __restrict__ h2T, const float* __restrict__ w3,
    const float* __restrict__ b3, float* __restrict__ out) {
  int g = threadIdx.x;
  float z0 = b3[0], z1 = b3[1];
  for (int k = 0; k < M_DIM; ++k) {
    float v = h2T[(size_t)k * N_GRAPHS + g];
    z0 += v * w3[k];
    z1 += v * w3[M_DIM + k];
  }
  float mz = fmaxf(z0, z1);
  float lse = mz + logf(expf(z0 - mz) + expf(z1 - mz));
  out[g * 2 + 0] = z0 - lse;
  out[g * 2 + 1] = z1 - lse;
}

// ---------------- launch ----------------
extern "C" void kernel_launch(void* const* d_in, const int* in_sizes, int n_in,
                              void* d_out, int out_size, void* d_ws, size_t ws_size,
                              hipStream_t stream) {
  const float* x       = (const float*)d_in[0];
  const int*   row     = (const int*)d_in[1];
  const int*   col     = row + N_EDGES;
  const int*   batch   = (const int*)d_in[2];
  const float* w_rel   = (const float*)d_in[4];
  const float* b_rel   = (const float*)d_in[5];
  const float* w_root  = (const float*)d_in[6];
  const float* norm0_g = (const float*)d_in[7];
  const float* norm0_b = (const float*)d_in[8];
  const float* lin_w   = (const float*)d_in[9];
  const float* lin_b   = (const float*)d_in[10];
  const float* bnh_g   = (const float*)d_in[11];
  const float* bnh_b   = (const float*)d_in[12];
  const float* bno_g   = (const float*)d_in[13];
  const float* bno_b   = (const float*)d_in[14];
  const float* w1      = (const float*)d_in[15];
  const float* b1      = (const float*)d_in[16];
  const float* w2      = (const float*)d_in[17];
  const float* b2      = (const float*)d_in[18];
  const float* w3      = (const float*)d_in[19];
  const float* b3      = (const float*)d_in[20];
  float* out = (float*)d_out;

  char* ws = (char*)d_ws;
  size_t off = 0;
  auto allocb = [&](size_t nbytes) {
    char* p = ws + off;
    off += ((nbytes + 255) & ~(size_t)255);
    return p;
  };
  // ---- zero-init region ----
  int*   degA      = (int*)allocb(N_NODES * 4);
  int*   degB      = (int*)allocb(N_NODES * 4);
  float* gsum      = (float*)allocb((size_t)N_GRAPHS * M_DIM * 4);
  float* colsumsq  = (float*)allocb(M_DIM * 4);
  float* colsum8   = (float*)allocb(8 * PROJ * 4);
  float* colsq8    = (float*)allocb(8 * PROJ * 4);
  size_t zero_bytes = off;
  // ---- no init needed ----
  float* cnt    = (float*)allocb(N_GRAPHS * 4);
  int*   gstart = (int*)allocb((N_GRAPHS + 1) * 4);
  float* bn_s   = (float*)allocb(PROJ * 4);
  float* bn_t   = (float*)allocb(PROJ * 4);
  float* lin_b2 = (float*)allocb(M_DIM * 4);
  int*   offsA = (int*)allocb(N_NODES * 4);
  int*   cursA = (int*)allocb(N_NODES * 4);
  int*   offsB = (int*)allocb(N_NODES * 4);
  int*   cursB = (int*)allocb(N_NODES * 4);
  int*   bsumA = (int*)allocb(SCAN_BLK * 4);
  int*   bsumB = (int*)allocb(SCAN_BLK * 4);
  int*   eidxA = (int*)allocb(N_EDGES * 4);
  int*   eidxB = (int*)allocb(N_EDGES * 4);
  unsigned short* Hcb   = (unsigned short*)allocb((size_t)N_NODES * HC_DIM * 2);
  unsigned short* xnb   = (unsigned short*)allocb((size_t)N_NODES * 256 * 2);
  unsigned short* wcatb = (unsigned short*)allocb(128 * 256 * 2);
  unsigned short* linwb = (unsigned short*)allocb(384 * 384 * 2);
  float* gmax  = (float*)allocb((size_t)N_GRAPHS * M_DIM * 4);
  float* gmin  = (float*)allocb((size_t)N_GRAPHS * M_DIM * 4);
  float* h0T   = (float*)allocb((size_t)CAT_DIM * N_GRAPHS * 4);
  float* h1T   = (float*)allocb((size_t)H1_DIM * N_GRAPHS * 4);
  float* h2T   = (float*)allocb((size_t)M_DIM * N_GRAPHS * 4);

  const int NB = (N_NODES + SCAN_BLK - 1) / SCAN_BLK;

  hipMemsetAsync(d_ws, 0, zero_bytes, stream);
  init_kernel<<<(N_NODES + 255) / 256, 256, 0, stream>>>(batch, gmax, gmin, gstart);
  cnt_from_bounds_kernel<<<1, 128, 0, stream>>>(gstart, cnt);

  // CSR build (XCD-partitioned hist + fill; scans fused A/B via blockIdx.y)
  hist_part_kernel<<<NPART * NPB, 256, 0, stream>>>(row, col, degA, degB);
  scan1_kernel<<<dim3(NB, 2), SCAN_BLK, 0, stream>>>(degA, degB, offsA, offsB, bsumA, bsumB, N_NODES);
  scan2_kernel<<<dim3(1, 2), SCAN_BLK, 0, stream>>>(bsumA, bsumB, NB);
  scan3_kernel<<<dim3(NB, 2), SCAN_BLK, 0, stream>>>(offsA, offsB, bsumA, bsumB, cursA, cursB, N_NODES);
  fill_csr_part_kernel<<<NPART * NPB, 256, 0, stream>>>(row, col, cursA, eidxA, cursB, eidxB);

  // conversions (independent)
  convert_x_kernel<<<(N_NODES * 32 + 255) / 256, 256, 0, stream>>>(x, xnb);
  convert_wcat_kernel<<<(128 * 64 + 255) / 256, 256, 0, stream>>>(w_rel, w_root, wcatb);

  // neigh (bf16) = gather of bf16 x -> xnb[:,0:128]
  gather_bf16_kernel<<<(N_NODES * 16 + 255) / 256, 256, 0, stream>>>(
      xnb + 128, offsA, cursA, eidxA, xnb, 256, 256);
  // conv GEMM -> Hcb[:,0:128] bf16 RAW (pre-BN) + fused column stats
  gemm_conv_mfma<<<NROWB, 256, 0, stream>>>(xnb, wcatb, b_rel, Hcb, colsum8, colsq8);
  bn_prep_kernel<<<1, 128, 0, stream>>>(colsum8, colsq8, norm0_g, norm0_b, bn_s, bn_t);
  // fold BN0 into masked-GEMM weights/bias (small, after bn_prep)
  convert_linw_kernel<<<(384 * 96 + 255) / 256, 256, 0, stream>>>(lin_w, bn_s, linwb);
  linb_fold_kernel<<<3, 128, 0, stream>>>(lin_w, lin_b, bn_t, lin_b2);
  // H1 = A @ BN(X) = bn_s*(A@Xraw) + deg*bn_t -> Hcb[:,128:256]
  gather_bn_kernel<<<(N_NODES * 16 + 255) / 256, 256, 0, stream>>>(
      Hcb, offsB, cursB, eidxB, bn_s, bn_t, Hcb + 128, HC_DIM, HC_DIM);
  // H2 = A @ H1 -> Hcb[:,256:384]
  gather_bf16_kernel<<<(N_NODES * 16 + 255) / 256, 256, 0, stream>>>(
      Hcb + 128, offsB, cursB, eidxB, Hcb + 256, HC_DIM, HC_DIM);
  // masked GEMM (BN0-folded) + fused pooling (LPT 1D grid)
  gemm_mask_mfma<<<NROWB * 3, 256, 0, stream>>>(
      Hcb, linwb, lin_b2, batch, gsum, gmax, gmin, colsumsq);
  // readout
  finalize_kernel<<<M_DIM, 128, 0, stream>>>(gsum, gmax, gmin, colsumsq, cnt,
                                             bnh_g, bnh_b, bno_g, bno_b, h0T);
  mlp_kernel<<<H1_DIM, 128, 0, stream>>>(h0T, w1, b1, h1T, CAT_DIM, 1);
  mlp_kernel<<<M_DIM, 128, 0, stream>>>(h1T, w2, b2, h2T, H1_DIM, 1);
  head_kernel<<<1, 128, 0, stream>>>(h2T, w3, b3, out);
}